// Round 5
// baseline (402.537 us; speedup 1.0000x reference)
//
#include <hip/hip_runtime.h>
#include <hip/hip_bf16.h>
#include <stdint.h>

#define EMBED 256
#define HEADS 8
#define LEVELS 4
#define POINTS 4
#define HEAD_DIM 32
#define HPAD 128
#define WPAD 128
#define LN_EPS 1e-5f

typedef unsigned short u16;
typedef __attribute__((ext_vector_type(8))) short bf16x8v;
typedef __attribute__((ext_vector_type(4))) float f32x4;

static __device__ __forceinline__ float bu2f(u16 u) {
  return __uint_as_float(((unsigned)u) << 16);
}
static __device__ __forceinline__ u16 f2bu(float f) {   // fp32 -> bf16 RNE
  unsigned x = __float_as_uint(f);
  return (u16)((x + 0x7fffu + ((x >> 16) & 1u)) >> 16);
}
static __device__ __forceinline__ float loadf(const void* p, size_t i, int isbf) {
  return isbf ? bu2f(((const u16*)p)[i]) : ((const float*)p)[i];
}
static __device__ __forceinline__ int imin(int a, int b) { return a < b ? a : b; }

static __device__ __forceinline__ void cp16(const u16* g, u16* l) {
  __builtin_amdgcn_global_load_lds((const __attribute__((address_space(1))) unsigned*)g,
                                   (__attribute__((address_space(3))) unsigned*)l, 16, 0, 0);
}

// ------------- dtype probe -------------
__global__ __launch_bounds__(256) void detect_kernel(const unsigned* __restrict__ q,
                                                     int* __restrict__ flag) {
  int t = threadIdx.x;
  __shared__ int s[256];
  unsigned u = q[t * 13 + 1];
  unsigned e = (u >> 7) & 0xFF;
  s[t] = (e >= 116 && e <= 130) ? 1 : 0;
  __syncthreads();
  for (int st = 128; st > 0; st >>= 1) { if (t < st) s[t] += s[t + st]; __syncthreads(); }
  if (t == 0) *flag = (s[0] > 200) ? 1 : 0;   // 1 => bf16 elements
}

// ------------- combined off/attn bias (fp32) -------------
__global__ __launch_bounds__(384) void boa_kernel(const void* __restrict__ b_off,
                                                  const void* __restrict__ b_attn,
                                                  float* __restrict__ boa,
                                                  const int* __restrict__ dflag) {
  int fl = *dflag;
  int t = threadIdx.x;
  boa[t] = (t < 256) ? loadf(b_off, t, fl) : loadf(b_attn, t - 256, fl);
}

// ------------- combined weight: Wt[n*256+k] = bf16( (W_q @ [W_off|W_attn])[k][n] )
// x = ln@W_q feeds ONLY the off/attn projections, so fold W_q in: one fp32 256x384
// GEMM at setup, removing the 20000-row GEMM-2 + its bf16 intermediate entirely.
__global__ __launch_bounds__(1024) void wcomb_kernel(const void* __restrict__ Wq,
                                                     const void* __restrict__ Woff,
                                                     const void* __restrict__ Wattn,
                                                     u16* __restrict__ Wt,
                                                     const int* __restrict__ dflag) {
  int fl = *dflag;
  int n0 = blockIdx.x * 32, k0 = blockIdx.y * 32;
  int tx = threadIdx.x & 31;   // n within tile
  int ty = threadIdx.x >> 5;   // k within tile
  __shared__ float Aq[32][33];
  __shared__ float Bo[32][33];
  float acc = 0.f;
  for (int j0 = 0; j0 < 256; j0 += 32) {
    Aq[ty][tx] = loadf(Wq, (size_t)(k0 + ty) * 256 + j0 + tx, fl);
    int n = n0 + tx;
    Bo[ty][tx] = (n < 256) ? loadf(Woff,  (size_t)(j0 + ty) * 256 + n,        fl)
                           : loadf(Wattn, (size_t)(j0 + ty) * 128 + (n - 256), fl);
    __syncthreads();
#pragma unroll
    for (int j = 0; j < 32; j++) acc += Aq[ty][j] * Bo[j][tx];
    __syncthreads();
  }
  Wt[(size_t)(n0 + tx) * 256 + k0 + ty] = f2bu(acc);
}

// ------------- coalesced tiled transpose: Wt[n*K+k] = bf16(W[k*N+n]) -------------
__global__ __launch_bounds__(256) void wtrans_kernel(const void* __restrict__ W,
                                                     u16* __restrict__ Wt,
                                                     int K, int N,
                                                     const int* __restrict__ dflag) {
  int fl = *dflag;
  __shared__ float tile[32][33];
  int tx = threadIdx.x & 31, ty = threadIdx.x >> 5;
  int k0 = blockIdx.x * 32, n0 = blockIdx.y * 32;
#pragma unroll
  for (int j = 0; j < 4; j++) {
    int r = ty + j * 8;
    tile[r][tx] = loadf(W, (size_t)(k0 + r) * N + n0 + tx, fl);
  }
  __syncthreads();
#pragma unroll
  for (int j = 0; j < 4; j++) {
    int n = ty + j * 8;
    Wt[(size_t)(n0 + n) * K + k0 + tx] = f2bu(tile[tx][n]);
  }
}

// ---------------- LayerNorm: wave-per-row, shuffle reductions, no LDS -------------
__global__ __launch_bounds__(256) void ln_kernel(const void* __restrict__ q,
                                                 const void* __restrict__ g,
                                                 const void* __restrict__ be,
                                                 u16* __restrict__ out, int Qn,
                                                 const int* __restrict__ dflag) {
  int fl = *dflag;
  int row = blockIdx.x * 4 + (threadIdx.x >> 6);
  int lane = threadIdx.x & 63;
  if (row >= Qn) return;
  float v0, v1, v2, v3;
  if (fl) {
    uint2 u = *(const uint2*)((const u16*)q + (size_t)row * 256 + lane * 4);
    v0 = bu2f((u16)(u.x & 0xffff)); v1 = bu2f((u16)(u.x >> 16));
    v2 = bu2f((u16)(u.y & 0xffff)); v3 = bu2f((u16)(u.y >> 16));
  } else {
    float4 f = *(const float4*)((const float*)q + (size_t)row * 256 + lane * 4);
    v0 = f.x; v1 = f.y; v2 = f.z; v3 = f.w;
  }
  float s = v0 + v1 + v2 + v3;
#pragma unroll
  for (int m = 1; m < 64; m <<= 1) s += __shfl_xor(s, m, 64);
  float mu = s * (1.f / 256.f);
  float c0 = v0 - mu, c1 = v1 - mu, c2 = v2 - mu, c3 = v3 - mu;
  float s2 = c0 * c0 + c1 * c1 + c2 * c2 + c3 * c3;
#pragma unroll
  for (int m = 1; m < 64; m <<= 1) s2 += __shfl_xor(s2, m, 64);
  float r = rsqrtf(s2 * (1.f / 256.f) + LN_EPS);
  float o0 = c0 * r * loadf(g, lane * 4 + 0, fl) + loadf(be, lane * 4 + 0, fl);
  float o1 = c1 * r * loadf(g, lane * 4 + 1, fl) + loadf(be, lane * 4 + 1, fl);
  float o2 = c2 * r * loadf(g, lane * 4 + 2, fl) + loadf(be, lane * 4 + 2, fl);
  float o3 = c3 * r * loadf(g, lane * 4 + 3, fl) + loadf(be, lane * 4 + 3, fl);
  uint2 w;
  w.x = (unsigned)f2bu(o0) | ((unsigned)f2bu(o1) << 16);
  w.y = (unsigned)f2bu(o2) | ((unsigned)f2bu(o3) << 16);
  *(uint2*)(out + (size_t)row * 256 + lane * 4) = w;
}

// ---------------- MFMA GEMM (round-0 proven form), single-buffer staging ----------
// C[M,N] = A[M,K] @ Bt[N,K]^T (+bias)(+resid). 128x128 tile, 4 waves, BK=32.
// ABF: A bf16 (cp16 DMA). else: A flag-dtype (VGPR convert staging).
// OUTMODE: 0 fp32, 1 bf16, 2 flag. BiasC: 0 bias fp32, 2 bias flag dtype.
template <int OUTMODE, bool ABF>
__global__ __launch_bounds__(256) void mfma_gemm(const void* __restrict__ A,
                                                 const u16* __restrict__ Bt,
                                                 const void* __restrict__ bias, int BiasC,
                                                 const void* __restrict__ resid,
                                                 void* __restrict__ Cv,
                                                 int M, int N, int K,
                                                 const int* __restrict__ dflag) {
  int fl = *dflag;
  __shared__ u16 As[4096];
  __shared__ u16 Bs[4096];
  int tid = threadIdx.x;
  int m0 = blockIdx.x * 128, n0 = blockIdx.y * 128;
  int wave = tid >> 6, lane = tid & 63;
  int quad = lane >> 4, r16 = lane & 15;
  int wm = (wave >> 1) * 64, wn = (wave & 1) * 64;

  f32x4 acc[4][4];
#pragma unroll
  for (int i = 0; i < 4; i++)
#pragma unroll
    for (int j = 0; j < 4; j++) acc[i][j] = (f32x4){0.f, 0.f, 0.f, 0.f};

  int p0 = tid, p1 = tid + 256;
  int r0 = p0 >> 2, c0 = (p0 & 3) * 8;
  int r1 = p1 >> 2, c1 = (p1 & 3) * 8;
  int ra0 = imin(m0 + r0, M - 1), ra1 = imin(m0 + r1, M - 1);

  const u16*   Ab = (const u16*)A;
  const float* Af = (const float*)A;

  for (int k0 = 0; k0 < K; k0 += 32) {
    __syncthreads();   // previous iteration's LDS reads complete
    if (ABF) {
      cp16(Ab + (size_t)ra0 * K + k0 + c0, &As[p0 * 8]);
      cp16(Ab + (size_t)ra1 * K + k0 + c1, &As[p1 * 8]);
    } else if (fl) {
      *(int4*)&As[p0 * 8] = *(const int4*)(Ab + (size_t)ra0 * K + k0 + c0);
      *(int4*)&As[p1 * 8] = *(const int4*)(Ab + (size_t)ra1 * K + k0 + c1);
    } else {
      float4 f00 = *(const float4*)(Af + (size_t)ra0 * K + k0 + c0);
      float4 f01 = *(const float4*)(Af + (size_t)ra0 * K + k0 + c0 + 4);
      float4 f10 = *(const float4*)(Af + (size_t)ra1 * K + k0 + c1);
      float4 f11 = *(const float4*)(Af + (size_t)ra1 * K + k0 + c1 + 4);
      u16* d0 = &As[p0 * 8];
      d0[0] = f2bu(f00.x); d0[1] = f2bu(f00.y); d0[2] = f2bu(f00.z); d0[3] = f2bu(f00.w);
      d0[4] = f2bu(f01.x); d0[5] = f2bu(f01.y); d0[6] = f2bu(f01.z); d0[7] = f2bu(f01.w);
      u16* d1 = &As[p1 * 8];
      d1[0] = f2bu(f10.x); d1[1] = f2bu(f10.y); d1[2] = f2bu(f10.z); d1[3] = f2bu(f10.w);
      d1[4] = f2bu(f11.x); d1[5] = f2bu(f11.y); d1[6] = f2bu(f11.z); d1[7] = f2bu(f11.w);
    }
    cp16(Bt + (size_t)(n0 + r0) * K + k0 + c0, &Bs[p0 * 8]);
    cp16(Bt + (size_t)(n0 + r1) * K + k0 + c1, &Bs[p1 * 8]);
    __syncthreads();

    bf16x8v a[4], b[4];
#pragma unroll
    for (int i = 0; i < 4; i++)
      a[i] = *(const bf16x8v*)&As[(wm + i * 16 + r16) * 32 + quad * 8];
#pragma unroll
    for (int j = 0; j < 4; j++)
      b[j] = *(const bf16x8v*)&Bs[(wn + j * 16 + r16) * 32 + quad * 8];
#pragma unroll
    for (int i = 0; i < 4; i++)
#pragma unroll
      for (int j = 0; j < 4; j++)
        acc[i][j] = __builtin_amdgcn_mfma_f32_16x16x32_bf16(a[i], b[j], acc[i][j], 0, 0, 0);
  }

  // ---- epilogue ----
  int obf = (OUTMODE == 2) ? fl : OUTMODE;
  int bfl = (BiasC == 2) ? fl : 0;
  if (bias) {   // bias added in source (pre-shuffle) layout: col = n0+wn+j*16+r16
#pragma unroll
    for (int j = 0; j < 4; j++) {
      float bv = loadf(bias, n0 + wn + j * 16 + r16, bfl);
#pragma unroll
      for (int i = 0; i < 4; i++)
#pragma unroll
        for (int reg = 0; reg < 4; reg++) acc[i][j][reg] += bv;
    }
  }

  if (obf) {
    int sl0 = (quad << 4) | ((2 * r16) & 15);
    int sl1 = sl0 + 1;
    bool lohalf = (r16 < 8);
#pragma unroll
    for (int i = 0; i < 4; i++) {
#pragma unroll
      for (int jp = 0; jp < 2; jp++) {
#pragma unroll
        for (int reg = 0; reg < 4; reg++) {
          float vA = acc[i][jp * 2][reg], vB = acc[i][jp * 2 + 1][reg];
          float a0 = __shfl(vA, sl0), a1 = __shfl(vA, sl1);
          float b0 = __shfl(vB, sl0), b1 = __shfl(vB, sl1);
          float lo = lohalf ? a0 : b0;
          float hi = lohalf ? a1 : b1;
          int row = m0 + wm + i * 16 + quad * 4 + reg;
          if (row < M) {
            size_t base = (size_t)row * N + n0 + wn + jp * 32 + 2 * r16;
            if (resid) {
              lo += loadf(resid, base, fl);
              hi += loadf(resid, base + 1, fl);
            }
            unsigned pk = (unsigned)f2bu(lo) | ((unsigned)f2bu(hi) << 16);
            *(unsigned*)((u16*)Cv + base) = pk;
          }
        }
      }
    }
  } else {
#pragma unroll
    for (int j = 0; j < 4; j++) {
      int col = n0 + wn + j * 16 + r16;
#pragma unroll
      for (int i = 0; i < 4; i++) {
#pragma unroll
        for (int reg = 0; reg < 4; reg++) {
          int row = m0 + wm + i * 16 + quad * 4 + reg;
          if (row < M) {
            float v = acc[i][j][reg];
            if (resid) v += loadf(resid, (size_t)row * N + col, fl);
            ((float*)Cv)[(size_t)row * N + col] = v;
          }
        }
      }
    }
  }
}

// ---------------- Streaming value GEMM, COMPACT valid rows -------------------------
// Padded grid is [B][128][128][L][E], but level l only has (128>>l)^2 valid (y,x)
// positions: 21760 of 65536 rows/batch. sample2 masks OOB and never reads padded
// rows, so compute ONLY valid rows: 3x less FLOPs/fetch/write, layout unchanged.
// 21760/128 = 170 tiles/batch; all level boundaries fall on tile boundaries.
__global__ __launch_bounds__(512) void val_gemm(const void* __restrict__ A,
                                                const u16* __restrict__ Bt,
                                                const void* __restrict__ bias,
                                                u16* __restrict__ Cv,
                                                const int* __restrict__ dflag) {
  int fl = *dflag;
  __shared__ u16 As[128 * 256];          // [row][swizzled 16B chunk], 64 KiB
  int tid = threadIdx.x;
  int blk = blockIdx.x;
  int b   = blk / 170;
  int cb  = blk % 170;
  int l, ibase;
  if (cb < 128)      { l = 0; ibase = cb * 128; }
  else if (cb < 160) { l = 1; ibase = (cb - 128) * 128; }
  else if (cb < 168) { l = 2; ibase = (cb - 160) * 128; }
  else               { l = 3; ibase = (cb - 168) * 128; }
  int shift = 7 - l;                     // log2(W_l), W_l = 128>>l
  int mask  = (128 >> l) - 1;
  int rowbase = b * 65536 + l;           // padded row = rowbase + y*512 + x*4

  int wave = tid >> 6, lane = tid & 63;
  int quad = lane >> 4, r16 = lane & 15;
  int wm = (wave >> 2) * 64, wn = (wave & 3) * 64;   // 2(M) x 4(N) wave grid

  // ---- phase 1: valid-row A -> bf16 swizzled LDS ----
  if (fl) {
    const uint4* A16 = (const uint4*)A;  // 16B units, 32 per row
#pragma unroll
    for (int it = 0; it < 8; it++) {
      int g = it * 512 + tid;            // 16B unit within tile (4096 total)
      int r = g >> 5, c = g & 31;
      int i = ibase + r;
      size_t rowg = (size_t)rowbase + (i >> shift) * 512 + (i & mask) * 4;
      uint4 v = A16[rowg * 32 + c];
      *(uint4*)&As[r * 256 + ((c ^ (r & 7)) * 8)] = v;
    }
  } else {
    const float4* A4 = (const float4*)A; // 64 float4 per row
#pragma unroll
    for (int p = 0; p < 2; p++) {
      float4 f[8];
#pragma unroll
      for (int q = 0; q < 8; q++) {
        int g = (p * 8 + q) * 512 + tid; // float4 unit within tile (8192 total)
        int i = ibase + (g >> 6);
        size_t rowg = (size_t)rowbase + (i >> shift) * 512 + (i & mask) * 4;
        f[q] = A4[rowg * 64 + (g & 63)];
      }
#pragma unroll
      for (int q = 0; q < 8; q++) {
        int g = (p * 8 + q) * 512 + tid;
        int r = g >> 6, cw = g & 63;
        int c = cw >> 1, sub = cw & 1;
        uint2 w;
        w.x = (unsigned)f2bu(f[q].x) | ((unsigned)f2bu(f[q].y) << 16);
        w.y = (unsigned)f2bu(f[q].z) | ((unsigned)f2bu(f[q].w) << 16);
        *(uint2*)&As[r * 256 + ((c ^ (r & 7)) * 8) + sub * 4] = w;
      }
    }
  }
  __syncthreads();                        // the only barrier

  // ---- phase 2: 8 K-steps, no barriers ----
  f32x4 acc[4][4];
#pragma unroll
  for (int i = 0; i < 4; i++)
#pragma unroll
    for (int j = 0; j < 4; j++) acc[i][j] = (f32x4){0.f, 0.f, 0.f, 0.f};

  int arow[4], arl[4];
#pragma unroll
  for (int i = 0; i < 4; i++) {
    arow[i] = (wm + i * 16 + r16) * 256;  // u16 row base
    arl[i]  = (wm + i * 16 + r16) & 7;    // swizzle key
  }
  const u16* bbase[4];
#pragma unroll
  for (int j = 0; j < 4; j++)
    bbase[j] = Bt + (size_t)(wn + j * 16 + r16) * 256 + quad * 8;

#pragma unroll
  for (int t = 0; t < 8; t++) {
    bf16x8v b4[4];
#pragma unroll
    for (int j = 0; j < 4; j++)
      b4[j] = *(const bf16x8v*)(bbase[j] + t * 32);
    bf16x8v a4[4];
#pragma unroll
    for (int i = 0; i < 4; i++) {
      int chunk = ((t << 2) | quad) ^ arl[i];
      a4[i] = *(const bf16x8v*)&As[arow[i] + chunk * 8];
    }
#pragma unroll
    for (int i = 0; i < 4; i++)
#pragma unroll
      for (int j = 0; j < 4; j++)
        acc[i][j] = __builtin_amdgcn_mfma_f32_16x16x32_bf16(a4[i], b4[j], acc[i][j], 0, 0, 0);
  }

  // ---- epilogue: bias + shuffle-pack bf16 store to mapped padded rows ----
#pragma unroll
  for (int j = 0; j < 4; j++) {
    float bv = loadf(bias, wn + j * 16 + r16, fl);
#pragma unroll
    for (int i = 0; i < 4; i++)
#pragma unroll
      for (int reg = 0; reg < 4; reg++) acc[i][j][reg] += bv;
  }
  int sl0 = (quad << 4) | ((2 * r16) & 15);
  int sl1 = sl0 + 1;
  bool lohalf = (r16 < 8);
#pragma unroll
  for (int i = 0; i < 4; i++) {
#pragma unroll
    for (int jp = 0; jp < 2; jp++) {
#pragma unroll
      for (int reg = 0; reg < 4; reg++) {
        float vA = acc[i][jp * 2][reg], vB = acc[i][jp * 2 + 1][reg];
        float a0 = __shfl(vA, sl0), a1 = __shfl(vA, sl1);
        float b0 = __shfl(vB, sl0), b1 = __shfl(vB, sl1);
        float lo = lohalf ? a0 : b0;
        float hi = lohalf ? a1 : b1;
        int rloc = wm + i * 16 + quad * 4 + reg;
        int ii = ibase + rloc;
        size_t rowg = (size_t)rowbase + (ii >> shift) * 512 + (ii & mask) * 4;
        size_t base = rowg * 256 + wn + jp * 32 + 2 * r16;
        unsigned pk = (unsigned)f2bu(lo) | ((unsigned)f2bu(hi) << 16);
        *(unsigned*)(Cv + base) = pk;
      }
    }
  }
}

// ---------------- Deformable sampling v3: uint4 gathers + corner shuffle-reduce ----
// Final phase re-mapped: 16 threads/head = (corner c4 in [0,4)) x (16B chunk d4 in
// [0,4)). Each thread: 16 lp iterations x ONE uint4 load (8 bf16) weighted by
// Cw[lp][c4] -> 8 partials; corners summed via 2x shfl_xor; c4==0 stores 16B.
// 4x fewer VMEM instructions than the per-dword version, same bytes/coalescing.
__global__ __launch_bounds__(256) void sample2_kernel(const float* __restrict__ oa,
                                                      const void* __restrict__ qsp,
                                                      const int* __restrict__ qbo, int nb,
                                                      const int* __restrict__ lss,
                                                      const u16* __restrict__ value,
                                                      u16* __restrict__ samp, int Qn,
                                                      const int* __restrict__ dflag) {
  int fl = *dflag;
  int t = threadIdx.x;
  int q2 = t >> 7;
  int i7 = t & 127;
  int qb = blockIdx.x * 2;
  int q = imin(qb + q2, Qn - 1);

  __shared__ float Loff[2][256];
  __shared__ float Lw[2][128];
  __shared__ int   Lb[2];
  __shared__ int   Co[2][128][4];
  __shared__ float Cw[2][128][4];

  {
    const float* row = oa + (size_t)q * 384;
    float2 v = ((const float2*)row)[i7];
    Loff[q2][i7 * 2]     = v.x;
    Loff[q2][i7 * 2 + 1] = v.y;
    Lw[q2][i7] = row[256 + i7];
  }
  if (t < 2) {
    int qq = imin(qb + t, Qn - 1);
    int b = 0;
    for (int i = 1; i < nb; i++) if (qq >= qbo[i]) b = i;
    Lb[t] = b;
  }
  __syncthreads();

  if (t < 16) {
    int sq = t >> 3, h = t & 7;
    float* w = &Lw[sq][h * 16];
    float mx = w[0];
    for (int i = 1; i < 16; i++) mx = fmaxf(mx, w[i]);
    float s = 0.f;
    for (int i = 0; i < 16; i++) { float e = __expf(w[i] - mx); w[i] = e; s += e; }
    float inv = 1.f / s;
    for (int i = 0; i < 16; i++) w[i] *= inv;
  }
  __syncthreads();

  {
    int h = i7 >> 4, lp = i7 & 15, l = lp >> 2;
    int Hi = lss[l * 2], Wi = lss[l * 2 + 1];
    float Hl = (float)Hi, Wl = (float)Wi;
    float qy = loadf(qsp, (size_t)q * 2, fl);
    float qx = loadf(qsp, (size_t)q * 2 + 1, fl);
    float a  = Lw[q2][i7];
    float oy = Loff[q2][i7 * 2], ox = Loff[q2][i7 * 2 + 1];
    float py = (qy + oy / Hl) * Hl - 0.5f;
    float px = (qx + ox / Wl) * Wl - 0.5f;
    float y0f = floorf(py), x0f = floorf(px);
    float wy = py - y0f, wx = px - x0f;
    int y0 = (int)y0f, x0 = (int)x0f;
    int bbase = Lb[q2] * (HPAD * WPAD * LEVELS * EMBED);
#pragma unroll
    for (int c = 0; c < 4; c++) {
      int yi = y0 + (c >> 1), xi = x0 + (c & 1);
      float w = ((c >> 1) ? wy : 1.f - wy) * ((c & 1) ? wx : 1.f - wx);
      bool ok = (yi >= 0) & (yi < Hi) & (xi >= 0) & (xi < Wi);
      Co[q2][i7][c] = ok ? (bbase + ((yi * WPAD + xi) * LEVELS + l) * EMBED + h * HEAD_DIM) : 0;
      Cw[q2][i7][c] = ok ? (a * w) : 0.f;
    }
  }
  __syncthreads();

  {
    int h  = i7 >> 4;          // head
    int c4 = i7 & 3;           // corner
    int d4 = (i7 >> 2) & 3;    // 16B chunk within 64B head segment
    float a0 = 0.f, a1 = 0.f, a2 = 0.f, a3 = 0.f, a4 = 0.f, a5 = 0.f, a6 = 0.f, a7 = 0.f;
#pragma unroll
    for (int lp = 0; lp < 16; lp++) {
      int   off = Co[q2][h * 16 + lp][c4];
      float w   = Cw[q2][h * 16 + lp][c4];
      uint4 v = *(const uint4*)(value + off + d4 * 8);
      a0 += w * __uint_as_float(v.x << 16); a1 += w * __uint_as_float(v.x & 0xffff0000u);
      a2 += w * __uint_as_float(v.y << 16); a3 += w * __uint_as_float(v.y & 0xffff0000u);
      a4 += w * __uint_as_float(v.z << 16); a5 += w * __uint_as_float(v.z & 0xffff0000u);
      a6 += w * __uint_as_float(v.w << 16); a7 += w * __uint_as_float(v.w & 0xffff0000u);
    }
    // sum the 4 corners (lanes differing in bits 0-1)
#pragma unroll
    for (int m = 1; m <= 2; m <<= 1) {
      a0 += __shfl_xor(a0, m, 64); a1 += __shfl_xor(a1, m, 64);
      a2 += __shfl_xor(a2, m, 64); a3 += __shfl_xor(a3, m, 64);
      a4 += __shfl_xor(a4, m, 64); a5 += __shfl_xor(a5, m, 64);
      a6 += __shfl_xor(a6, m, 64); a7 += __shfl_xor(a7, m, 64);
    }
    if (c4 == 0 && qb + q2 < Qn) {
      uint4 pk;
      pk.x = (unsigned)f2bu(a0) | ((unsigned)f2bu(a1) << 16);
      pk.y = (unsigned)f2bu(a2) | ((unsigned)f2bu(a3) << 16);
      pk.z = (unsigned)f2bu(a4) | ((unsigned)f2bu(a5) << 16);
      pk.w = (unsigned)f2bu(a6) | ((unsigned)f2bu(a7) << 16);
      *(uint4*)(samp + (size_t)(qb + q2) * 256 + h * 32 + d4 * 8) = pk;
    }
  }
}

extern "C" void kernel_launch(void* const* d_in, const int* in_sizes, int n_in,
                              void* d_out, int out_size, void* d_ws, size_t ws_size,
                              hipStream_t stream) {
  const void* query  = d_in[0];
  const void* qsp    = d_in[1];
  const int*  qbo    = (const int*)d_in[2];
  const void* sfm    = d_in[3];
  const int*  lss    = (const int*)d_in[4];
  const void* gamma  = d_in[5];
  const void* beta   = d_in[6];
  const void* W_q    = d_in[7];
  const void* W_off  = d_in[8];
  const void* b_off  = d_in[9];
  const void* W_attn = d_in[10];
  const void* b_attn = d_in[11];
  const void* W_val  = d_in[12];
  const void* b_val  = d_in[13];
  const void* W_out  = d_in[14];

  const int Q  = in_sizes[0] / EMBED;      // 20000
  const int nb = in_sizes[2] - 1;          // 2
  const int MV = in_sizes[3] / EMBED;      // 131072
  const int B  = MV / (HPAD * WPAD * LEVELS);   // 2

  char* ws = (char*)d_ws;
  size_t o = 0;
  auto alloc = [&](size_t bytes) { size_t r = o; o = (o + bytes + 255) & ~(size_t)255; return r; };
  u16*   xln   = (u16*)(ws + alloc((size_t)Q * EMBED * sizeof(u16)));
  float* oaw   = (float*)(ws + alloc((size_t)Q * 384 * sizeof(float)));
  u16*   valw  = (u16*)(ws + alloc((size_t)MV * EMBED * sizeof(u16)));
  u16*   sampw = (u16*)(ws + alloc((size_t)Q * EMBED * sizeof(u16)));
  u16*   wtoa  = (u16*)(ws + alloc(384 * 256 * sizeof(u16)));
  u16*   wtval = (u16*)(ws + alloc(256 * 256 * sizeof(u16)));
  u16*   wtout = (u16*)(ws + alloc(256 * 256 * sizeof(u16)));
  float* boa   = (float*)(ws + alloc(384 * sizeof(float)));
  int*   dflag = (int*)(ws + alloc(256));
  (void)ws_size;

  // 0) dtype probe + bias combine
  detect_kernel<<<1, 256, 0, stream>>>((const unsigned*)query, dflag);
  boa_kernel<<<1, 384, 0, stream>>>(b_off, b_attn, boa, dflag);

  // 0b) combined weight (W_q folded into off/attn) + transposes to bf16 [N][K]
  wcomb_kernel<<<dim3(12, 8), 1024, 0, stream>>>(W_q, W_off, W_attn, wtoa, dflag);
  wtrans_kernel<<<dim3(8, 8), 256, 0, stream>>>(W_val, wtval, 256, 256, dflag);
  wtrans_kernel<<<dim3(8, 8), 256, 0, stream>>>(W_out, wtout, 256, 256, dflag);

  // 1) LayerNorm -> bf16 (wave-per-row)
  ln_kernel<<<(Q + 3) / 4, 256, 0, stream>>>(query, gamma, beta, xln, Q, dflag);

  const int GQ = (Q + 127) / 128;
  // 2+3+4) [off|attn] = ln_out @ Wc + boa  (fp32 out, N=384; GEMM-2 folded away)
  mfma_gemm<0, true><<<dim3(GQ, 3), 256, 0, stream>>>(xln, wtoa, boa, 0, nullptr, oaw, Q, 384, 256, dflag);
  // 5) value = sfm @ W_val + b_val  (bf16 out; compact valid rows, 170 tiles/batch)
  val_gemm<<<dim3(B * 170), 512, 0, stream>>>(sfm, wtval, b_val, valw, dflag);
  // 6) sampling (bf16 out)
  sample2_kernel<<<(Q + 1) / 2, 256, 0, stream>>>(oaw, qsp, qbo, nb, lss, valw, sampw, Q, dflag);
  // 7) out = sampw @ W_out + residual(query)  (flag dtype out)
  mfma_gemm<2, true><<<dim3(GQ, 2), 256, 0, stream>>>(sampw, wtout, nullptr, 0, query, d_out, Q, 256, 256, dflag);
}

// Round 6
// 373.179 us; speedup vs baseline: 1.0787x; 1.0787x over previous
//
#include <hip/hip_runtime.h>
#include <hip/hip_bf16.h>
#include <stdint.h>

#define EMBED 256
#define HEADS 8
#define LEVELS 4
#define POINTS 4
#define HEAD_DIM 32
#define HPAD 128
#define WPAD 128
#define LN_EPS 1e-5f

typedef unsigned short u16;
typedef __attribute__((ext_vector_type(8))) short bf16x8v;
typedef __attribute__((ext_vector_type(4))) float f32x4;

static __device__ __forceinline__ float bu2f(u16 u) {
  return __uint_as_float(((unsigned)u) << 16);
}
static __device__ __forceinline__ u16 f2bu(float f) {   // fp32 -> bf16 RNE
  unsigned x = __float_as_uint(f);
  return (u16)((x + 0x7fffu + ((x >> 16) & 1u)) >> 16);
}
static __device__ __forceinline__ float loadf(const void* p, size_t i, int isbf) {
  return isbf ? bu2f(((const u16*)p)[i]) : ((const float*)p)[i];
}
static __device__ __forceinline__ int imin(int a, int b) { return a < b ? a : b; }

static __device__ __forceinline__ void cp16(const u16* g, u16* l) {
  __builtin_amdgcn_global_load_lds((const __attribute__((address_space(1))) unsigned*)g,
                                   (__attribute__((address_space(3))) unsigned*)l, 16, 0, 0);
}

// ------------- dtype probe -------------
__global__ __launch_bounds__(256) void detect_kernel(const unsigned* __restrict__ q,
                                                     int* __restrict__ flag) {
  int t = threadIdx.x;
  __shared__ int s[256];
  unsigned u = q[t * 13 + 1];
  unsigned e = (u >> 7) & 0xFF;
  s[t] = (e >= 116 && e <= 130) ? 1 : 0;
  __syncthreads();
  for (int st = 128; st > 0; st >>= 1) { if (t < st) s[t] += s[t + st]; __syncthreads(); }
  if (t == 0) *flag = (s[0] > 200) ? 1 : 0;   // 1 => bf16 elements
}

// ------------- combined off/attn bias (fp32) -------------
__global__ __launch_bounds__(384) void boa_kernel(const void* __restrict__ b_off,
                                                  const void* __restrict__ b_attn,
                                                  float* __restrict__ boa,
                                                  const int* __restrict__ dflag) {
  int fl = *dflag;
  int t = threadIdx.x;
  boa[t] = (t < 256) ? loadf(b_off, t, fl) : loadf(b_attn, t - 256, fl);
}

// ------------- combined weight: Wt[n*256+k] = bf16( (W_q @ [W_off|W_attn])[k][n] )
// x = ln@W_q feeds ONLY the off/attn projections, so fold W_q in: one fp32 256x384
// GEMM at setup, removing the 20000-row GEMM-2 + its bf16 intermediate entirely.
__global__ __launch_bounds__(1024) void wcomb_kernel(const void* __restrict__ Wq,
                                                     const void* __restrict__ Woff,
                                                     const void* __restrict__ Wattn,
                                                     u16* __restrict__ Wt,
                                                     const int* __restrict__ dflag) {
  int fl = *dflag;
  int n0 = blockIdx.x * 32, k0 = blockIdx.y * 32;
  int tx = threadIdx.x & 31;   // n within tile
  int ty = threadIdx.x >> 5;   // k within tile
  __shared__ float Aq[32][33];
  __shared__ float Bo[32][33];
  float acc = 0.f;
  for (int j0 = 0; j0 < 256; j0 += 32) {
    Aq[ty][tx] = loadf(Wq, (size_t)(k0 + ty) * 256 + j0 + tx, fl);
    int n = n0 + tx;
    Bo[ty][tx] = (n < 256) ? loadf(Woff,  (size_t)(j0 + ty) * 256 + n,        fl)
                           : loadf(Wattn, (size_t)(j0 + ty) * 128 + (n - 256), fl);
    __syncthreads();
#pragma unroll
    for (int j = 0; j < 32; j++) acc += Aq[ty][j] * Bo[j][tx];
    __syncthreads();
  }
  Wt[(size_t)(n0 + tx) * 256 + k0 + ty] = f2bu(acc);
}

// ------------- coalesced tiled transpose: Wt[n*K+k] = bf16(W[k*N+n]) -------------
__global__ __launch_bounds__(256) void wtrans_kernel(const void* __restrict__ W,
                                                     u16* __restrict__ Wt,
                                                     int K, int N,
                                                     const int* __restrict__ dflag) {
  int fl = *dflag;
  __shared__ float tile[32][33];
  int tx = threadIdx.x & 31, ty = threadIdx.x >> 5;
  int k0 = blockIdx.x * 32, n0 = blockIdx.y * 32;
#pragma unroll
  for (int j = 0; j < 4; j++) {
    int r = ty + j * 8;
    tile[r][tx] = loadf(W, (size_t)(k0 + r) * N + n0 + tx, fl);
  }
  __syncthreads();
#pragma unroll
  for (int j = 0; j < 4; j++) {
    int n = ty + j * 8;
    Wt[(size_t)(n0 + n) * K + k0 + tx] = f2bu(tile[tx][n]);
  }
}

// ---------------- LayerNorm: wave-per-row, shuffle reductions, no LDS -------------
__global__ __launch_bounds__(256) void ln_kernel(const void* __restrict__ q,
                                                 const void* __restrict__ g,
                                                 const void* __restrict__ be,
                                                 u16* __restrict__ out, int Qn,
                                                 const int* __restrict__ dflag) {
  int fl = *dflag;
  int row = blockIdx.x * 4 + (threadIdx.x >> 6);
  int lane = threadIdx.x & 63;
  if (row >= Qn) return;
  float v0, v1, v2, v3;
  if (fl) {
    uint2 u = *(const uint2*)((const u16*)q + (size_t)row * 256 + lane * 4);
    v0 = bu2f((u16)(u.x & 0xffff)); v1 = bu2f((u16)(u.x >> 16));
    v2 = bu2f((u16)(u.y & 0xffff)); v3 = bu2f((u16)(u.y >> 16));
  } else {
    float4 f = *(const float4*)((const float*)q + (size_t)row * 256 + lane * 4);
    v0 = f.x; v1 = f.y; v2 = f.z; v3 = f.w;
  }
  float s = v0 + v1 + v2 + v3;
#pragma unroll
  for (int m = 1; m < 64; m <<= 1) s += __shfl_xor(s, m, 64);
  float mu = s * (1.f / 256.f);
  float c0 = v0 - mu, c1 = v1 - mu, c2 = v2 - mu, c3 = v3 - mu;
  float s2 = c0 * c0 + c1 * c1 + c2 * c2 + c3 * c3;
#pragma unroll
  for (int m = 1; m < 64; m <<= 1) s2 += __shfl_xor(s2, m, 64);
  float r = rsqrtf(s2 * (1.f / 256.f) + LN_EPS);
  float o0 = c0 * r * loadf(g, lane * 4 + 0, fl) + loadf(be, lane * 4 + 0, fl);
  float o1 = c1 * r * loadf(g, lane * 4 + 1, fl) + loadf(be, lane * 4 + 1, fl);
  float o2 = c2 * r * loadf(g, lane * 4 + 2, fl) + loadf(be, lane * 4 + 2, fl);
  float o3 = c3 * r * loadf(g, lane * 4 + 3, fl) + loadf(be, lane * 4 + 3, fl);
  uint2 w;
  w.x = (unsigned)f2bu(o0) | ((unsigned)f2bu(o1) << 16);
  w.y = (unsigned)f2bu(o2) | ((unsigned)f2bu(o3) << 16);
  *(uint2*)(out + (size_t)row * 256 + lane * 4) = w;
}

// ---------------- MFMA GEMM (round-0 proven form), single-buffer staging ----------
// C[M,N] = A[M,K] @ Bt[N,K]^T (+bias)(+resid). 128x128 tile, 4 waves, BK=32.
// ABF: A bf16 (cp16 DMA). else: A flag-dtype (VGPR convert staging).
// OUTMODE: 0 fp32, 1 bf16, 2 flag. BiasC: 0 bias fp32, 2 bias flag dtype.
template <int OUTMODE, bool ABF>
__global__ __launch_bounds__(256) void mfma_gemm(const void* __restrict__ A,
                                                 const u16* __restrict__ Bt,
                                                 const void* __restrict__ bias, int BiasC,
                                                 const void* __restrict__ resid,
                                                 void* __restrict__ Cv,
                                                 int M, int N, int K,
                                                 const int* __restrict__ dflag) {
  int fl = *dflag;
  __shared__ u16 As[4096];
  __shared__ u16 Bs[4096];
  int tid = threadIdx.x;
  int m0 = blockIdx.x * 128, n0 = blockIdx.y * 128;
  int wave = tid >> 6, lane = tid & 63;
  int quad = lane >> 4, r16 = lane & 15;
  int wm = (wave >> 1) * 64, wn = (wave & 1) * 64;

  f32x4 acc[4][4];
#pragma unroll
  for (int i = 0; i < 4; i++)
#pragma unroll
    for (int j = 0; j < 4; j++) acc[i][j] = (f32x4){0.f, 0.f, 0.f, 0.f};

  int p0 = tid, p1 = tid + 256;
  int r0 = p0 >> 2, c0 = (p0 & 3) * 8;
  int r1 = p1 >> 2, c1 = (p1 & 3) * 8;
  int ra0 = imin(m0 + r0, M - 1), ra1 = imin(m0 + r1, M - 1);

  const u16*   Ab = (const u16*)A;
  const float* Af = (const float*)A;

  for (int k0 = 0; k0 < K; k0 += 32) {
    __syncthreads();   // previous iteration's LDS reads complete
    if (ABF) {
      cp16(Ab + (size_t)ra0 * K + k0 + c0, &As[p0 * 8]);
      cp16(Ab + (size_t)ra1 * K + k0 + c1, &As[p1 * 8]);
    } else if (fl) {
      *(int4*)&As[p0 * 8] = *(const int4*)(Ab + (size_t)ra0 * K + k0 + c0);
      *(int4*)&As[p1 * 8] = *(const int4*)(Ab + (size_t)ra1 * K + k0 + c1);
    } else {
      float4 f00 = *(const float4*)(Af + (size_t)ra0 * K + k0 + c0);
      float4 f01 = *(const float4*)(Af + (size_t)ra0 * K + k0 + c0 + 4);
      float4 f10 = *(const float4*)(Af + (size_t)ra1 * K + k0 + c1);
      float4 f11 = *(const float4*)(Af + (size_t)ra1 * K + k0 + c1 + 4);
      u16* d0 = &As[p0 * 8];
      d0[0] = f2bu(f00.x); d0[1] = f2bu(f00.y); d0[2] = f2bu(f00.z); d0[3] = f2bu(f00.w);
      d0[4] = f2bu(f01.x); d0[5] = f2bu(f01.y); d0[6] = f2bu(f01.z); d0[7] = f2bu(f01.w);
      u16* d1 = &As[p1 * 8];
      d1[0] = f2bu(f10.x); d1[1] = f2bu(f10.y); d1[2] = f2bu(f10.z); d1[3] = f2bu(f10.w);
      d1[4] = f2bu(f11.x); d1[5] = f2bu(f11.y); d1[6] = f2bu(f11.z); d1[7] = f2bu(f11.w);
    }
    cp16(Bt + (size_t)(n0 + r0) * K + k0 + c0, &Bs[p0 * 8]);
    cp16(Bt + (size_t)(n0 + r1) * K + k0 + c1, &Bs[p1 * 8]);
    __syncthreads();

    bf16x8v a[4], b[4];
#pragma unroll
    for (int i = 0; i < 4; i++)
      a[i] = *(const bf16x8v*)&As[(wm + i * 16 + r16) * 32 + quad * 8];
#pragma unroll
    for (int j = 0; j < 4; j++)
      b[j] = *(const bf16x8v*)&Bs[(wn + j * 16 + r16) * 32 + quad * 8];
#pragma unroll
    for (int i = 0; i < 4; i++)
#pragma unroll
      for (int j = 0; j < 4; j++)
        acc[i][j] = __builtin_amdgcn_mfma_f32_16x16x32_bf16(a[i], b[j], acc[i][j], 0, 0, 0);
  }

  // ---- epilogue ----
  int obf = (OUTMODE == 2) ? fl : OUTMODE;
  int bfl = (BiasC == 2) ? fl : 0;
  if (bias) {   // bias added in source (pre-shuffle) layout: col = n0+wn+j*16+r16
#pragma unroll
    for (int j = 0; j < 4; j++) {
      float bv = loadf(bias, n0 + wn + j * 16 + r16, bfl);
#pragma unroll
      for (int i = 0; i < 4; i++)
#pragma unroll
        for (int reg = 0; reg < 4; reg++) acc[i][j][reg] += bv;
    }
  }

  if (obf) {
    int sl0 = (quad << 4) | ((2 * r16) & 15);
    int sl1 = sl0 + 1;
    bool lohalf = (r16 < 8);
#pragma unroll
    for (int i = 0; i < 4; i++) {
#pragma unroll
      for (int jp = 0; jp < 2; jp++) {
#pragma unroll
        for (int reg = 0; reg < 4; reg++) {
          float vA = acc[i][jp * 2][reg], vB = acc[i][jp * 2 + 1][reg];
          float a0 = __shfl(vA, sl0), a1 = __shfl(vA, sl1);
          float b0 = __shfl(vB, sl0), b1 = __shfl(vB, sl1);
          float lo = lohalf ? a0 : b0;
          float hi = lohalf ? a1 : b1;
          int row = m0 + wm + i * 16 + quad * 4 + reg;
          if (row < M) {
            size_t base = (size_t)row * N + n0 + wn + jp * 32 + 2 * r16;
            if (resid) {
              lo += loadf(resid, base, fl);
              hi += loadf(resid, base + 1, fl);
            }
            unsigned pk = (unsigned)f2bu(lo) | ((unsigned)f2bu(hi) << 16);
            *(unsigned*)((u16*)Cv + base) = pk;
          }
        }
      }
    }
  } else {
#pragma unroll
    for (int j = 0; j < 4; j++) {
      int col = n0 + wn + j * 16 + r16;
#pragma unroll
      for (int i = 0; i < 4; i++) {
#pragma unroll
        for (int reg = 0; reg < 4; reg++) {
          int row = m0 + wm + i * 16 + quad * 4 + reg;
          if (row < M) {
            float v = acc[i][j][reg];
            if (resid) v += loadf(resid, (size_t)row * N + col, fl);
            ((float*)Cv)[(size_t)row * N + col] = v;
          }
        }
      }
    }
  }
}

// ---------------- Streaming value GEMM, COMPACT valid rows -------------------------
// Padded grid is [B][128][128][L][E], but level l only has (128>>l)^2 valid (y,x)
// positions: 21760 of 65536 rows/batch. sample2 masks OOB and never reads padded
// rows, so compute ONLY valid rows: 3x less FLOPs/fetch/write, layout unchanged.
// 21760/128 = 170 tiles/batch; all level boundaries fall on tile boundaries.
__global__ __launch_bounds__(512) void val_gemm(const void* __restrict__ A,
                                                const u16* __restrict__ Bt,
                                                const void* __restrict__ bias,
                                                u16* __restrict__ Cv,
                                                const int* __restrict__ dflag) {
  int fl = *dflag;
  __shared__ u16 As[128 * 256];          // [row][swizzled 16B chunk], 64 KiB
  int tid = threadIdx.x;
  int blk = blockIdx.x;
  int b   = blk / 170;
  int cb  = blk % 170;
  int l, ibase;
  if (cb < 128)      { l = 0; ibase = cb * 128; }
  else if (cb < 160) { l = 1; ibase = (cb - 128) * 128; }
  else if (cb < 168) { l = 2; ibase = (cb - 160) * 128; }
  else               { l = 3; ibase = (cb - 168) * 128; }
  int shift = 7 - l;                     // log2(W_l), W_l = 128>>l
  int mask  = (128 >> l) - 1;
  int rowbase = b * 65536 + l;           // padded row = rowbase + y*512 + x*4

  int wave = tid >> 6, lane = tid & 63;
  int quad = lane >> 4, r16 = lane & 15;
  int wm = (wave >> 2) * 64, wn = (wave & 3) * 64;   // 2(M) x 4(N) wave grid

  // ---- phase 1: valid-row A -> bf16 swizzled LDS ----
  if (fl) {
    const uint4* A16 = (const uint4*)A;  // 16B units, 32 per row
#pragma unroll
    for (int it = 0; it < 8; it++) {
      int g = it * 512 + tid;            // 16B unit within tile (4096 total)
      int r = g >> 5, c = g & 31;
      int i = ibase + r;
      size_t rowg = (size_t)rowbase + (i >> shift) * 512 + (i & mask) * 4;
      uint4 v = A16[rowg * 32 + c];
      *(uint4*)&As[r * 256 + ((c ^ (r & 7)) * 8)] = v;
    }
  } else {
    const float4* A4 = (const float4*)A; // 64 float4 per row
#pragma unroll
    for (int p = 0; p < 2; p++) {
      float4 f[8];
#pragma unroll
      for (int q = 0; q < 8; q++) {
        int g = (p * 8 + q) * 512 + tid; // float4 unit within tile (8192 total)
        int i = ibase + (g >> 6);
        size_t rowg = (size_t)rowbase + (i >> shift) * 512 + (i & mask) * 4;
        f[q] = A4[rowg * 64 + (g & 63)];
      }
#pragma unroll
      for (int q = 0; q < 8; q++) {
        int g = (p * 8 + q) * 512 + tid;
        int r = g >> 6, cw = g & 63;
        int c = cw >> 1, sub = cw & 1;
        uint2 w;
        w.x = (unsigned)f2bu(f[q].x) | ((unsigned)f2bu(f[q].y) << 16);
        w.y = (unsigned)f2bu(f[q].z) | ((unsigned)f2bu(f[q].w) << 16);
        *(uint2*)&As[r * 256 + ((c ^ (r & 7)) * 8) + sub * 4] = w;
      }
    }
  }
  __syncthreads();                        // the only barrier

  // ---- phase 2: 8 K-steps, no barriers ----
  f32x4 acc[4][4];
#pragma unroll
  for (int i = 0; i < 4; i++)
#pragma unroll
    for (int j = 0; j < 4; j++) acc[i][j] = (f32x4){0.f, 0.f, 0.f, 0.f};

  int arow[4], arl[4];
#pragma unroll
  for (int i = 0; i < 4; i++) {
    arow[i] = (wm + i * 16 + r16) * 256;  // u16 row base
    arl[i]  = (wm + i * 16 + r16) & 7;    // swizzle key
  }
  const u16* bbase[4];
#pragma unroll
  for (int j = 0; j < 4; j++)
    bbase[j] = Bt + (size_t)(wn + j * 16 + r16) * 256 + quad * 8;

#pragma unroll
  for (int t = 0; t < 8; t++) {
    bf16x8v b4[4];
#pragma unroll
    for (int j = 0; j < 4; j++)
      b4[j] = *(const bf16x8v*)(bbase[j] + t * 32);
    bf16x8v a4[4];
#pragma unroll
    for (int i = 0; i < 4; i++) {
      int chunk = ((t << 2) | quad) ^ arl[i];
      a4[i] = *(const bf16x8v*)&As[arow[i] + chunk * 8];
    }
#pragma unroll
    for (int i = 0; i < 4; i++)
#pragma unroll
      for (int j = 0; j < 4; j++)
        acc[i][j] = __builtin_amdgcn_mfma_f32_16x16x32_bf16(a4[i], b4[j], acc[i][j], 0, 0, 0);
  }

  // ---- epilogue: bias + shuffle-pack bf16 store to mapped padded rows ----
#pragma unroll
  for (int j = 0; j < 4; j++) {
    float bv = loadf(bias, wn + j * 16 + r16, fl);
#pragma unroll
    for (int i = 0; i < 4; i++)
#pragma unroll
      for (int reg = 0; reg < 4; reg++) acc[i][j][reg] += bv;
  }
  int sl0 = (quad << 4) | ((2 * r16) & 15);
  int sl1 = sl0 + 1;
  bool lohalf = (r16 < 8);
#pragma unroll
  for (int i = 0; i < 4; i++) {
#pragma unroll
    for (int jp = 0; jp < 2; jp++) {
#pragma unroll
      for (int reg = 0; reg < 4; reg++) {
        float vA = acc[i][jp * 2][reg], vB = acc[i][jp * 2 + 1][reg];
        float a0 = __shfl(vA, sl0), a1 = __shfl(vA, sl1);
        float b0 = __shfl(vB, sl0), b1 = __shfl(vB, sl1);
        float lo = lohalf ? a0 : b0;
        float hi = lohalf ? a1 : b1;
        int rloc = wm + i * 16 + quad * 4 + reg;
        int ii = ibase + rloc;
        size_t rowg = (size_t)rowbase + (ii >> shift) * 512 + (ii & mask) * 4;
        size_t base = rowg * 256 + wn + jp * 32 + 2 * r16;
        unsigned pk = (unsigned)f2bu(lo) | ((unsigned)f2bu(hi) << 16);
        *(unsigned*)(Cv + base) = pk;
      }
    }
  }
}

// ---------------- Deformable sampling v2 (proven r0-r4 form; v3 regressed ~+30us) --
// Final gather phase: thread (h, d2 in [0,16)); per lp all 4 corner dwords loaded
// per-thread; 16 consecutive lanes read each 64B corner-segment contiguously.
__global__ __launch_bounds__(256) void sample2_kernel(const float* __restrict__ oa,
                                                      const void* __restrict__ qsp,
                                                      const int* __restrict__ qbo, int nb,
                                                      const int* __restrict__ lss,
                                                      const u16* __restrict__ value,
                                                      u16* __restrict__ samp, int Qn,
                                                      const int* __restrict__ dflag) {
  int fl = *dflag;
  int t = threadIdx.x;
  int q2 = t >> 7;
  int i7 = t & 127;
  int qb = blockIdx.x * 2;
  int q = imin(qb + q2, Qn - 1);

  __shared__ float Loff[2][256];
  __shared__ float Lw[2][128];
  __shared__ int   Lb[2];
  __shared__ int   Co[2][128][4];
  __shared__ float Cw[2][128][4];

  {
    const float* row = oa + (size_t)q * 384;
    float2 v = ((const float2*)row)[i7];
    Loff[q2][i7 * 2]     = v.x;
    Loff[q2][i7 * 2 + 1] = v.y;
    Lw[q2][i7] = row[256 + i7];
  }
  if (t < 2) {
    int qq = imin(qb + t, Qn - 1);
    int b = 0;
    for (int i = 1; i < nb; i++) if (qq >= qbo[i]) b = i;
    Lb[t] = b;
  }
  __syncthreads();

  if (t < 16) {
    int sq = t >> 3, h = t & 7;
    float* w = &Lw[sq][h * 16];
    float mx = w[0];
    for (int i = 1; i < 16; i++) mx = fmaxf(mx, w[i]);
    float s = 0.f;
    for (int i = 0; i < 16; i++) { float e = __expf(w[i] - mx); w[i] = e; s += e; }
    float inv = 1.f / s;
    for (int i = 0; i < 16; i++) w[i] *= inv;
  }
  __syncthreads();

  {
    int h = i7 >> 4, lp = i7 & 15, l = lp >> 2;
    int Hi = lss[l * 2], Wi = lss[l * 2 + 1];
    float Hl = (float)Hi, Wl = (float)Wi;
    float qy = loadf(qsp, (size_t)q * 2, fl);
    float qx = loadf(qsp, (size_t)q * 2 + 1, fl);
    float a  = Lw[q2][i7];
    float oy = Loff[q2][i7 * 2], ox = Loff[q2][i7 * 2 + 1];
    float py = (qy + oy / Hl) * Hl - 0.5f;
    float px = (qx + ox / Wl) * Wl - 0.5f;
    float y0f = floorf(py), x0f = floorf(px);
    float wy = py - y0f, wx = px - x0f;
    int y0 = (int)y0f, x0 = (int)x0f;
    int bbase = Lb[q2] * (HPAD * WPAD * LEVELS * EMBED);
#pragma unroll
    for (int c = 0; c < 4; c++) {
      int yi = y0 + (c >> 1), xi = x0 + (c & 1);
      float w = ((c >> 1) ? wy : 1.f - wy) * ((c & 1) ? wx : 1.f - wx);
      bool ok = (yi >= 0) & (yi < Hi) & (xi >= 0) & (xi < Wi);
      Co[q2][i7][c] = ok ? (bbase + ((yi * WPAD + xi) * LEVELS + l) * EMBED + h * HEAD_DIM) : 0;
      Cw[q2][i7][c] = ok ? (a * w) : 0.f;
    }
  }
  __syncthreads();

  {
    int h = (t >> 4) & 7;
    int d2 = t & 15;
    float ax = 0.f, ay = 0.f;
#pragma unroll
    for (int lp = 0; lp < 16; lp++) {
      int4   o4 = *(const int4*)&Co[q2][h * 16 + lp][0];
      float4 w4 = *(const float4*)&Cw[q2][h * 16 + lp][0];
      unsigned v;
      v = *(const unsigned*)(value + o4.x + d2 * 2);
      ax += w4.x * __uint_as_float(v << 16); ay += w4.x * __uint_as_float(v & 0xffff0000u);
      v = *(const unsigned*)(value + o4.y + d2 * 2);
      ax += w4.y * __uint_as_float(v << 16); ay += w4.y * __uint_as_float(v & 0xffff0000u);
      v = *(const unsigned*)(value + o4.z + d2 * 2);
      ax += w4.z * __uint_as_float(v << 16); ay += w4.z * __uint_as_float(v & 0xffff0000u);
      v = *(const unsigned*)(value + o4.w + d2 * 2);
      ax += w4.w * __uint_as_float(v << 16); ay += w4.w * __uint_as_float(v & 0xffff0000u);
    }
    if (qb + q2 < Qn) {
      unsigned pk = (unsigned)f2bu(ax) | ((unsigned)f2bu(ay) << 16);
      *(unsigned*)(samp + (size_t)(qb + q2) * 256 + h * 32 + d2 * 2) = pk;
    }
  }
}

extern "C" void kernel_launch(void* const* d_in, const int* in_sizes, int n_in,
                              void* d_out, int out_size, void* d_ws, size_t ws_size,
                              hipStream_t stream) {
  const void* query  = d_in[0];
  const void* qsp    = d_in[1];
  const int*  qbo    = (const int*)d_in[2];
  const void* sfm    = d_in[3];
  const int*  lss    = (const int*)d_in[4];
  const void* gamma  = d_in[5];
  const void* beta   = d_in[6];
  const void* W_q    = d_in[7];
  const void* W_off  = d_in[8];
  const void* b_off  = d_in[9];
  const void* W_attn = d_in[10];
  const void* b_attn = d_in[11];
  const void* W_val  = d_in[12];
  const void* b_val  = d_in[13];
  const void* W_out  = d_in[14];

  const int Q  = in_sizes[0] / EMBED;      // 20000
  const int nb = in_sizes[2] - 1;          // 2
  const int MV = in_sizes[3] / EMBED;      // 131072
  const int B  = MV / (HPAD * WPAD * LEVELS);   // 2

  char* ws = (char*)d_ws;
  size_t o = 0;
  auto alloc = [&](size_t bytes) { size_t r = o; o = (o + bytes + 255) & ~(size_t)255; return r; };
  u16*   xln   = (u16*)(ws + alloc((size_t)Q * EMBED * sizeof(u16)));
  float* oaw   = (float*)(ws + alloc((size_t)Q * 384 * sizeof(float)));
  u16*   valw  = (u16*)(ws + alloc((size_t)MV * EMBED * sizeof(u16)));
  u16*   sampw = (u16*)(ws + alloc((size_t)Q * EMBED * sizeof(u16)));
  u16*   wtoa  = (u16*)(ws + alloc(384 * 256 * sizeof(u16)));
  u16*   wtval = (u16*)(ws + alloc(256 * 256 * sizeof(u16)));
  u16*   wtout = (u16*)(ws + alloc(256 * 256 * sizeof(u16)));
  float* boa   = (float*)(ws + alloc(384 * sizeof(float)));
  int*   dflag = (int*)(ws + alloc(256));
  (void)ws_size;

  // 0) dtype probe + bias combine
  detect_kernel<<<1, 256, 0, stream>>>((const unsigned*)query, dflag);
  boa_kernel<<<1, 384, 0, stream>>>(b_off, b_attn, boa, dflag);

  // 0b) combined weight (W_q folded into off/attn) + transposes to bf16 [N][K]
  wcomb_kernel<<<dim3(12, 8), 1024, 0, stream>>>(W_q, W_off, W_attn, wtoa, dflag);
  wtrans_kernel<<<dim3(8, 8), 256, 0, stream>>>(W_val, wtval, 256, 256, dflag);
  wtrans_kernel<<<dim3(8, 8), 256, 0, stream>>>(W_out, wtout, 256, 256, dflag);

  // 1) LayerNorm -> bf16 (wave-per-row)
  ln_kernel<<<(Q + 3) / 4, 256, 0, stream>>>(query, gamma, beta, xln, Q, dflag);

  const int GQ = (Q + 127) / 128;
  // 2+3+4) [off|attn] = ln_out @ Wc + boa  (fp32 out, N=384; GEMM-2 folded away)
  mfma_gemm<0, true><<<dim3(GQ, 3), 256, 0, stream>>>(xln, wtoa, boa, 0, nullptr, oaw, Q, 384, 256, dflag);
  // 5) value = sfm @ W_val + b_val  (bf16 out; compact valid rows, 170 tiles/batch)
  val_gemm<<<dim3(B * 170), 512, 0, stream>>>(sfm, wtval, b_val, valw, dflag);
  // 6) sampling (bf16 out; proven v2 gather)
  sample2_kernel<<<(Q + 1) / 2, 256, 0, stream>>>(oaw, qsp, qbo, nb, lss, valw, sampw, Q, dflag);
  // 7) out = sampw @ W_out + residual(query)  (flag dtype out)
  mfma_gemm<2, true><<<dim3(GQ, 2), 256, 0, stream>>>(sampw, wtout, nullptr, 0, query, d_out, Q, 256, 256, dflag);
}